// Round 9
// baseline (108.750 us; speedup 1.0000x reference)
//
#include <hip/hip_runtime.h>
#include <hip/hip_bf16.h>

// B=8, T=4096, C=32, D=64. Causal, no 1/sqrt(D) scaling.
constexpr int Bc = 8;
constexpr int Tt = 4096;
constexpr int Dd = 64;

typedef __attribute__((ext_vector_type(8))) short short8;   // 8 bf16 = 4 VGPRs
typedef __attribute__((ext_vector_type(4))) float floatx4;  // MFMA C/D frag
typedef uint4   __attribute__((may_alias)) uint4_a;
typedef short8  __attribute__((may_alias)) short8_a;
typedef ushort4 __attribute__((may_alias)) ushort4_a;
typedef float4  __attribute__((may_alias)) float4_a;

#define MFMA16(A, B, C) __builtin_amdgcn_mfma_f32_16x16x32_bf16(A, B, C, 0, 0, 0)
constexpr float LOG2E = 1.4426950408889634f;

// ---- fast fp32 -> bf16: round-half-up (u + 0x8000), pack 2 via v_perm ----
__device__ __forceinline__ unsigned rnd16(float x) {
    unsigned u; __builtin_memcpy(&u, &x, 4); return u + 0x8000u;
}
__device__ __forceinline__ unsigned pk_bf2(float lo, float hi) {
    return __builtin_amdgcn_perm(rnd16(hi), rnd16(lo), 0x07060302);
}
__device__ __forceinline__ ushort4 pack4(floatx4 d) {
    union { unsigned u[2]; ushort4 v; } r;
    r.u[0] = pk_bf2(d[0], d[1]);
    r.u[1] = pk_bf2(d[2], d[3]);
    return r.v;
}
__device__ __forceinline__ short8 cvt8(float4 a, float4 b) {
    union { unsigned u[4]; short8 s; } r;
    r.u[0] = pk_bf2(a.x, a.y);
    r.u[1] = pk_bf2(a.z, a.w);
    r.u[2] = pk_bf2(b.x, b.y);
    r.u[3] = pk_bf2(b.z, b.w);
    return r.s;
}

// ---------------------------------------------------------------------------
// Associativity-refactored fused attention.
//   S = x (WqWk^T) x^T : G = (log2e Wq)Wk^T [32x32] once per block; per phase
//   Y = x·G (64q x 32, the effective Q); per tile S^T = x_k · Y^T with K=32
//   (ONE mfma per 16-key subtile, no K generation).
//   O = P·V = (P·x)·Wv : accumulate Z^T = x^T·P^T per wave (32c x 16q, 8 regs),
//   multiply by Wv once per phase after the additive group merge.
// Staging per tile = raw x-slab in two bf16 layouts ([key][c] for S's A-frags,
// [c][key] XOR-swizzled for Z's A-frags) = 8 KB, zero MFMAs.
// Block = 1024 thr = 16 waves = 4 split-K groups; balanced qt-pair per block
// (phases 63-pr, pr -> uniform 17 iters); no-max exp2 softmax (additive
// partials); LDS-only merges (R7 lesson: no global atomics).
// ---------------------------------------------------------------------------
__global__ __launch_bounds__(1024) void attn_kernel(
    const float* __restrict__ x,
    const float* __restrict__ Wk, const float* __restrict__ Wq,
    const float* __restrict__ Wv,
    float* __restrict__ out)
{
    __shared__ uint4 sStage[2048];  // 32 KB: group g at g*512: x_k [0..255], x^T [256..511]
    __shared__ uint4 sP[2048];      // 32 KB: wave P slots (w*128); [0..255] = sG/Y/l transient

    int b  = blockIdx.x & 7;
    int pr = blockIdx.x >> 3;            // 0..31
    int tid  = threadIdx.x;
    int wave = tid >> 6, lane = tid & 63;
    int group = wave >> 2, gw = wave & 3;
    int ln15 = lane & 15, quad = lane >> 4;
    int tid_g = tid & 255;
    size_t bT = (size_t)b * Tt;

    // ---- Wv^T A-frags, resident: (m = d = 16t+ln15, k = c = quad*8+j) ----
    short8 wv_f[4];
    #pragma unroll
    for (int t = 0; t < 4; ++t) {
        int col = 16*t + ln15;
        union { unsigned u[4]; short8 s; } rv;
        #pragma unroll
        for (int jj = 0; jj < 4; ++jj) {
            const float* v0 = Wv + (quad*8 + 2*jj) * 64 + col;
            rv.u[jj] = pk_bf2(v0[0], v0[64]);
        }
        wv_f[t] = rv.s;
    }

    // ---- G = (log2e Wq)·Wk^T [32x32], wave 0 computes + stages G^T bf16 ----
    if (wave == 0) {
        floatx4 gC[2][2];
        #pragma unroll
        for (int mt = 0; mt < 2; ++mt)
            #pragma unroll
            for (int nt = 0; nt < 2; ++nt) gC[mt][nt] = (floatx4){0.f,0.f,0.f,0.f};
        #pragma unroll
        for (int kt = 0; kt < 2; ++kt) {
            short8 aG[2], bG[2];
            #pragma unroll
            for (int mt = 0; mt < 2; ++mt) {
                const float* qp = Wq + (ln15 + 16*mt)*64 + 32*kt + quad*8;
                float4 a = ((const float4_a*)qp)[0], bb = ((const float4_a*)qp)[1];
                a.x*=LOG2E; a.y*=LOG2E; a.z*=LOG2E; a.w*=LOG2E;
                bb.x*=LOG2E; bb.y*=LOG2E; bb.z*=LOG2E; bb.w*=LOG2E;
                aG[mt] = cvt8(a, bb);
                const float* kp = Wk + (ln15 + 16*mt)*64 + 32*kt + quad*8;
                bG[mt] = cvt8(((const float4_a*)kp)[0], ((const float4_a*)kp)[1]);
            }
            #pragma unroll
            for (int mt = 0; mt < 2; ++mt)
                #pragma unroll
                for (int nt = 0; nt < 2; ++nt)
                    gC[mt][nt] = MFMA16(aG[mt], bG[nt], gC[mt][nt]);
        }
        // D[c][c'] C-layout (col=c'=ln15+16nt, row=c=16mt+quad*4+r)
        // store G^T [c'][c] bf16 (32 rows x 64 B)
        unsigned short* sGh = (unsigned short*)sP;
        #pragma unroll
        for (int mt = 0; mt < 2; ++mt)
            #pragma unroll
            for (int nt = 0; nt < 2; ++nt)
                *(ushort4_a*)(sGh + (16*nt + ln15)*32 + 16*mt + quad*4)
                    = pack4(gC[mt][nt]);
    }
    __syncthreads();
    short8 gt[2];   // G^T A-frags: (m = c' = 16mt+ln15, k = c = quad*8+j)
    #pragma unroll
    for (int mt = 0; mt < 2; ++mt) {
        union { uint4 u; short8 s; } g;
        g.u = sP[(16*mt + ln15)*4 + quad];
        gt[mt] = g.s;
    }
    __syncthreads();   // gt reads done before Y-regen overwrites sG area

    const int stB = group * 512;         // group's staging base (uint4)
    const int cT = tid_g & 31, kgT = tid_g >> 5;  // x^T staging: (feature, key-octet-pair base)
    unsigned short* sYh = (unsigned short*)sP;

    #pragma unroll
    for (int phase = 0; phase < 2; ++phase) {
        const int qtP = phase ? pr : 63 - pr;
        const int q0 = qtP * 64;
        const int qrow = q0 + gw*16 + ln15;

        // ---- Y = x·G regen: waves 0..7, (qsub = w&3, mt = w>>2), 1 MFMA ----
        if (wave < 8) {
            int qs = wave & 3, mt = wave >> 2;
            const float* xp = x + (bT + q0 + qs*16 + ln15)*32 + quad*8;
            short8 xq = cvt8(((const float4_a*)xp)[0], ((const float4_a*)xp)[1]);
            floatx4 d = (floatx4){0.f,0.f,0.f,0.f};
            d = MFMA16(gt[mt], xq, d);   // col=q=ln15, row=yc=16mt+quad*4+r
            *(ushort4_a*)(sYh + (qs*16 + ln15)*32 + 16*mt + quad*4) = pack4(d);
        }
        __syncthreads();
        short8 bq;   // Y B-frag: (n = q = ln15, k = yc = quad*8+j), K=32
        {
            union { uint4 u; short8 s; } t0;
            t0.u = sP[(gw*16 + ln15)*4 + quad];
            bq = t0.s;
        }

        floatx4 z4[2];    // Z^T acc: (col=q=ln15, row=c'=16mt+quad*4+r)
        z4[0] = (floatx4){0.f,0.f,0.f,0.f};
        z4[1] = (floatx4){0.f,0.f,0.f,0.f};
        float l_lane = 0.f;

        const int nIter = (qtP + 4) >> 2;
        float4 pX0, pX1; float pT[8];
        if (group <= qtP) {              // prologue x-slab prefetch (kt=group)
            const float* xp = x + (bT + group*64 + 16*gw + ln15)*32 + quad*8;
            pX0 = ((const float4_a*)xp)[0];
            pX1 = ((const float4_a*)xp)[1];
            const float* tp = x + (bT + group*64 + kgT*8)*32 + cT;
            #pragma unroll
            for (int j = 0; j < 8; ++j) pT[j] = tp[j*32];
        }

        for (int it = 0; it < nIter; ++it) {
            int kt = 4*it + group;
            bool active = (kt <= qtP);
            __syncthreads();             // prev compute done -> staging writable
            if (active) {
                // x_k [key][c]: rows 64 B, natural conflict-free b128
                union { short8 s; uint4 u; } xu;
                xu.s = cvt8(pX0, pX1);
                sStage[stB + (16*gw + ln15)*4 + quad] = xu.u;
                // x^T [c][key]: rows 128 B, chunk-XOR swizzled
                uint4 xt;
                xt.x = pk_bf2(pT[0], pT[1]); xt.y = pk_bf2(pT[2], pT[3]);
                xt.z = pk_bf2(pT[4], pT[5]); xt.w = pk_bf2(pT[6], pT[7]);
                sStage[stB + 256 + cT*8 + (kgT ^ (cT & 7))] = xt;
            }
            int ktn = kt + 4;            // prefetch next x-slab during compute
            if (ktn <= qtP) {
                const float* xp = x + (bT + ktn*64 + 16*gw + ln15)*32 + quad*8;
                pX0 = ((const float4_a*)xp)[0];
                pX1 = ((const float4_a*)xp)[1];
                const float* tp = x + (bT + ktn*64 + kgT*8)*32 + cT;
                #pragma unroll
                for (int j = 0; j < 8; ++j) pT[j] = tp[j*32];
            }
            __syncthreads();             // staged
            if (!active) continue;
            int k0 = kt * 64;

            // ---- S^T = x_k · Y^T : 4 MFMA (K=32) ----
            floatx4 s4[4];
            #pragma unroll
            for (int t = 0; t < 4; ++t) {
                union { uint4 u; short8 s; } a;
                a.u = sStage[stB + (16*t + ln15)*4 + quad];
                floatx4 c = (floatx4){0.f,0.f,0.f,0.f};
                c = MFMA16(a.s, bq, c);
                s4[t] = c;
            }

            // ---- p = exp2(s), mask only diagonal tile, P^T -> LDS ----
            unsigned long long* sP64 = (unsigned long long*)sP;
            const int pb = wave*256 + ln15*16;
            const int xk = ln15 & 14;
            if (kt == qtP) {             // block-uniform branch
                #pragma unroll
                for (int t = 0; t < 4; ++t) {
                    int keyb = k0 + 16*t + quad*4;
                    float p[4];
                    #pragma unroll
                    for (int r = 0; r < 4; ++r) {
                        p[r] = (keyb + r <= qrow) ? __builtin_amdgcn_exp2f(s4[t][r]) : 0.f;
                        l_lane += p[r];
                    }
                    unsigned long long pk =
                        ((unsigned long long)pk_bf2(p[2], p[3]) << 32) | pk_bf2(p[0], p[1]);
                    sP64[pb + ((4*t + quad) ^ xk)] = pk;
                }
            } else {
                #pragma unroll
                for (int t = 0; t < 4; ++t) {
                    float p[4];
                    #pragma unroll
                    for (int r = 0; r < 4; ++r) {
                        p[r] = __builtin_amdgcn_exp2f(s4[t][r]);
                        l_lane += p[r];
                    }
                    unsigned long long pk =
                        ((unsigned long long)pk_bf2(p[2], p[3]) << 32) | pk_bf2(p[0], p[1]);
                    sP64[pb + ((4*t + quad) ^ xk)] = pk;
                }
            }

            // ---- Z^T += x^T · P^T : 4 MFMA ----
            int h = (ln15 >> 1) & 7;
            union { uint4 u; short8 s; } p0, p1;
            p0.u = sP[wave*128 + ln15*8 + (quad ^ h)];
            p1.u = sP[wave*128 + ln15*8 + ((quad + 4) ^ h)];
            #pragma unroll
            for (int mt = 0; mt < 2; ++mt) {
                int row = 16*mt + ln15;
                union { uint4 u; short8 s; } a0, a1;
                a0.u = sStage[stB + 256 + row*8 + (quad ^ (ln15 & 7))];
                a1.u = sStage[stB + 256 + row*8 + ((4 + quad) ^ (ln15 & 7))];
                z4[mt] = MFMA16(a0.s, p0.s, z4[mt]);
                z4[mt] = MFMA16(a1.s, p1.s, z4[mt]);
            }
        }

        // ---- merge 4 groups' (Z^T, l) additively in LDS; group 0 finishes ----
        __syncthreads();                 // compute done; staging & sP free
        int li = gw*64 + lane;
        ((float*)sP)[wave*64 + lane] = l_lane;   // raw per-lane partial
        if (group != 0) {
            float4* st = (float4*)((char*)sStage + group*8192);
            st[li*2 + 0] = make_float4(z4[0][0], z4[0][1], z4[0][2], z4[0][3]);
            st[li*2 + 1] = make_float4(z4[1][0], z4[1][1], z4[1][2], z4[1][3]);
        }
        __syncthreads();
        if (group == 0) {
            float l = l_lane + ((float*)sP)[256 + li]
                    + ((float*)sP)[512 + li] + ((float*)sP)[768 + li];
            l += __shfl_xor(l, 16);      // quads hold disjoint key subsets
            l += __shfl_xor(l, 32);
            float inv = 1.f / l;
            #pragma unroll
            for (int g = 1; g < 4; ++g) {
                float4* st = (float4*)((char*)sStage + g*8192);
                float4 a = st[li*2 + 0], bb = st[li*2 + 1];
                z4[0][0]+=a.x; z4[0][1]+=a.y; z4[0][2]+=a.z; z4[0][3]+=a.w;
                z4[1][0]+=bb.x; z4[1][1]+=bb.y; z4[1][2]+=bb.z; z4[1][3]+=bb.w;
            }
            // pack merged Z as bf16 [q][c] (rows 64 B) into group-0 staging
            unsigned short* sZb = (unsigned short*)sStage;
            #pragma unroll
            for (int mt = 0; mt < 2; ++mt)
                *(ushort4_a*)(sZb + (gw*16 + ln15)*32 + 16*mt + quad*4) = pack4(z4[mt]);
            union { uint4 u; short8 s; } zb;   // same-wave readback (lgkmcnt)
            zb.u = sStage[(gw*16 + ln15)*4 + quad];
            // O^T = Wv^T · Z^T : 4 MFMA (K=32); col=q=ln15, row=d=16t+quad*4+r
            #pragma unroll
            for (int t = 0; t < 4; ++t) {
                floatx4 o = (floatx4){0.f,0.f,0.f,0.f};
                o = MFMA16(wv_f[t], zb.s, o);
                *(float4_a*)(out + (bT + q0 + gw*16 + ln15)*Dd + 16*t + quad*4)
                    = make_float4(o[0]*inv, o[1]*inv, o[2]*inv, o[3]*inv);
            }
        }
        __syncthreads();                 // merge/output done before next phase
    }
}

// ---------------------------------------------------------------------------
extern "C" void kernel_launch(void* const* d_in, const int* in_sizes, int n_in,
                              void* d_out, int out_size, void* d_ws, size_t ws_size,
                              hipStream_t stream)
{
    const float* x  = (const float*)d_in[0];
    const float* Wk = (const float*)d_in[1];   // setup_inputs order: x, Wk, Wq, Wv
    const float* Wq = (const float*)d_in[2];
    const float* Wv = (const float*)d_in[3];
    float* out = (float*)d_out;

    // 256 blocks (one per CU), 1024 threads, 64 KB LDS, uniform 17 iterations
    attn_kernel<<<Bc * 32, 1024, 0, stream>>>(x, Wk, Wq, Wv, out);
}

// Round 10
// 106.339 us; speedup vs baseline: 1.0227x; 1.0227x over previous
//
#include <hip/hip_runtime.h>
#include <hip/hip_bf16.h>

// B=8, T=4096, C=32, D=64. Causal, no 1/sqrt(D) scaling.
constexpr int Bc = 8;
constexpr int Tt = 4096;
constexpr int Dd = 64;

typedef __attribute__((ext_vector_type(8))) short short8;   // 8 bf16 = 4 VGPRs
typedef __attribute__((ext_vector_type(4))) float floatx4;  // MFMA C/D frag
typedef uint4   __attribute__((may_alias)) uint4_a;
typedef short8  __attribute__((may_alias)) short8_a;
typedef ushort4 __attribute__((may_alias)) ushort4_a;
typedef float4  __attribute__((may_alias)) float4_a;

#define MFMA16(A, B, C) __builtin_amdgcn_mfma_f32_16x16x32_bf16(A, B, C, 0, 0, 0)
constexpr float LOG2E = 1.4426950408889634f;

// ---- fast fp32 -> bf16: round-half-up (u + 0x8000), pack 2 via v_perm ----
__device__ __forceinline__ unsigned rnd16(float x) {
    unsigned u; __builtin_memcpy(&u, &x, 4); return u + 0x8000u;
}
__device__ __forceinline__ unsigned pk_bf2(float lo, float hi) {
    return __builtin_amdgcn_perm(rnd16(hi), rnd16(lo), 0x07060302);
}
__device__ __forceinline__ ushort4 pack4(floatx4 d) {
    union { unsigned u[2]; ushort4 v; } r;
    r.u[0] = pk_bf2(d[0], d[1]);
    r.u[1] = pk_bf2(d[2], d[3]);
    return r.v;
}
__device__ __forceinline__ short8 cvt8(float4 a, float4 b) {
    union { unsigned u[4]; short8 s; } r;
    r.u[0] = pk_bf2(a.x, a.y);
    r.u[1] = pk_bf2(a.z, a.w);
    r.u[2] = pk_bf2(b.x, b.y);
    r.u[3] = pk_bf2(b.z, b.w);
    return r.s;
}

// ---------------------------------------------------------------------------
// Associativity-refactored fused attention (R9 algebra):
//   G = (log2e Wq)Wk^T [32x32] once; Y = x·G per phase; S^T = x_k·Y^T (K=32);
//   Z^T += x^T·P^T accumulated per wave; O^T = Wv^T·Z^T once per phase.
// R10 execution fixes (R9 post-mortem):
//   - __launch_bounds__(1024,4): 128-VGPR budget, kills scratch spills
//     (R9: 45 MB of spill traffic at VGPR_Count=64).
//   - Double-buffered staging -> ONE __syncthreads per k-iteration (stage
//     buf it&1; prior readers separated by the it-1 barrier).
//   - Prefetch issued AFTER the barrier so no barrier vmcnt(0) drain ever
//     catches an in-flight prefetch; loads fly across the whole compute.
// Block = 1024 thr = 4 split-K groups x 4 waves; balanced qt-pair (63-pr, pr);
// no-max exp2 softmax (additive partials); LDS-only merges (R7 lesson).
// ---------------------------------------------------------------------------
__global__ __launch_bounds__(1024, 4) void attn_kernel(
    const float* __restrict__ x,
    const float* __restrict__ Wk, const float* __restrict__ Wq,
    const float* __restrict__ Wv,
    float* __restrict__ out)
{
    __shared__ uint4 sStage[4096];  // 64 KB: group g at g*1024; buf d at +d*512:
                                    //   x_k [0..255], x^T [256..511] (uint4)
    __shared__ uint4 sP[2048];      // 32 KB: wave P slots (w*128); sG/Y transient

    int b  = blockIdx.x & 7;
    int pr = blockIdx.x >> 3;            // 0..31
    int tid  = threadIdx.x;
    int wave = tid >> 6, lane = tid & 63;
    int group = wave >> 2, gw = wave & 3;
    int ln15 = lane & 15, quad = lane >> 4;
    int tid_g = tid & 255;
    size_t bT = (size_t)b * Tt;

    // ---- Wv^T A-frags, resident: (m = d = 16t+ln15, k = c = quad*8+j) ----
    short8 wv_f[4];
    #pragma unroll
    for (int t = 0; t < 4; ++t) {
        int col = 16*t + ln15;
        union { unsigned u[4]; short8 s; } rv;
        #pragma unroll
        for (int jj = 0; jj < 4; ++jj) {
            const float* v0 = Wv + (quad*8 + 2*jj) * 64 + col;
            rv.u[jj] = pk_bf2(v0[0], v0[64]);
        }
        wv_f[t] = rv.s;
    }

    // ---- G = (log2e Wq)·Wk^T [32x32], wave 0 computes + stages G^T bf16 ----
    if (wave == 0) {
        floatx4 gC[2][2];
        #pragma unroll
        for (int mt = 0; mt < 2; ++mt)
            #pragma unroll
            for (int nt = 0; nt < 2; ++nt) gC[mt][nt] = (floatx4){0.f,0.f,0.f,0.f};
        #pragma unroll
        for (int kt = 0; kt < 2; ++kt) {
            short8 aG[2], bG[2];
            #pragma unroll
            for (int mt = 0; mt < 2; ++mt) {
                const float* qp = Wq + (ln15 + 16*mt)*64 + 32*kt + quad*8;
                float4 a = ((const float4_a*)qp)[0], bb = ((const float4_a*)qp)[1];
                a.x*=LOG2E; a.y*=LOG2E; a.z*=LOG2E; a.w*=LOG2E;
                bb.x*=LOG2E; bb.y*=LOG2E; bb.z*=LOG2E; bb.w*=LOG2E;
                aG[mt] = cvt8(a, bb);
                const float* kp = Wk + (ln15 + 16*mt)*64 + 32*kt + quad*8;
                bG[mt] = cvt8(((const float4_a*)kp)[0], ((const float4_a*)kp)[1]);
            }
            #pragma unroll
            for (int mt = 0; mt < 2; ++mt)
                #pragma unroll
                for (int nt = 0; nt < 2; ++nt)
                    gC[mt][nt] = MFMA16(aG[mt], bG[nt], gC[mt][nt]);
        }
        unsigned short* sGh = (unsigned short*)sP;
        #pragma unroll
        for (int mt = 0; mt < 2; ++mt)
            #pragma unroll
            for (int nt = 0; nt < 2; ++nt)
                *(ushort4_a*)(sGh + (16*nt + ln15)*32 + 16*mt + quad*4)
                    = pack4(gC[mt][nt]);
    }
    __syncthreads();
    short8 gt[2];   // G^T A-frags: (m = c' = 16mt+ln15, k = c = quad*8+j)
    #pragma unroll
    for (int mt = 0; mt < 2; ++mt) {
        union { uint4 u; short8 s; } g;
        g.u = sP[(16*mt + ln15)*4 + quad];
        gt[mt] = g.s;
    }
    __syncthreads();   // gt reads done before Y-regen overwrites sG area

    const int gBase = group * 1024;      // group's 16 KB region (uint4 units)
    const int cT = tid_g & 31, kgT = tid_g >> 5;
    unsigned short* sYh = (unsigned short*)sP;

    #pragma unroll
    for (int phase = 0; phase < 2; ++phase) {
        const int qtP = phase ? pr : 63 - pr;
        const int q0 = qtP * 64;
        const int qrow = q0 + gw*16 + ln15;

        // ---- prologue x-slab prefetch (kt = group), issued before Y-regen ----
        float4 pX0, pX1; float pT[8];
        if (group <= qtP) {
            const float* xp = x + (bT + group*64 + 16*gw + ln15)*32 + quad*8;
            pX0 = ((const float4_a*)xp)[0];
            pX1 = ((const float4_a*)xp)[1];
            const float* tp = x + (bT + group*64 + kgT*8)*32 + cT;
            #pragma unroll
            for (int j = 0; j < 8; ++j) pT[j] = tp[j*32];
        }

        // ---- Y = x·G regen: waves 0..7, (qsub = w&3, mt = w>>2), 1 MFMA ----
        if (wave < 8) {
            int qs = wave & 3, mt = wave >> 2;
            const float* xp = x + (bT + q0 + qs*16 + ln15)*32 + quad*8;
            short8 xq = cvt8(((const float4_a*)xp)[0], ((const float4_a*)xp)[1]);
            floatx4 d = (floatx4){0.f,0.f,0.f,0.f};
            d = MFMA16(gt[mt], xq, d);   // col=q=ln15, row=yc=16mt+quad*4+r
            *(ushort4_a*)(sYh + (qs*16 + ln15)*32 + 16*mt + quad*4) = pack4(d);
        }
        __syncthreads();
        short8 bq;   // Y B-frag: (n = q = ln15, k = yc = quad*8+j), K=32
        {
            union { uint4 u; short8 s; } t0;
            t0.u = sP[(gw*16 + ln15)*4 + quad];
            bq = t0.s;
        }

        floatx4 z4[2];    // Z^T acc: (col=q=ln15, row=c'=16mt+quad*4+r)
        z4[0] = (floatx4){0.f,0.f,0.f,0.f};
        z4[1] = (floatx4){0.f,0.f,0.f,0.f};
        float l_lane = 0.f;

        const int nIter = (qtP + 4) >> 2;

        for (int it = 0; it < nIter; ++it) {
            int kt = 4*it + group;
            bool active = (kt <= qtP);
            const int stB = gBase + (it & 1) * 512;   // double buffer
            if (active) {   // stage from prefetch regs (vmcnt wait lands here)
                // x_k [key][c]: rows 64 B, natural conflict-free b128
                union { short8 s; uint4 u; } xu;
                xu.s = cvt8(pX0, pX1);
                sStage[stB + (16*gw + ln15)*4 + quad] = xu.u;
                // x^T [c][key]: rows 128 B, chunk-XOR swizzled
                uint4 xt;
                xt.x = pk_bf2(pT[0], pT[1]); xt.y = pk_bf2(pT[2], pT[3]);
                xt.z = pk_bf2(pT[4], pT[5]); xt.w = pk_bf2(pT[6], pT[7]);
                sStage[stB + 256 + cT*8 + (kgT ^ (cT & 7))] = xt;
            }
            __syncthreads();             // single barrier per iteration:
                                         // stage(it) visible; buf it&1 safe to
                                         // rewrite at it+2 (barrier it+1 between)
            int ktn = kt + 4;            // prefetch AFTER barrier: stays in
            if (ktn <= qtP) {            // flight across all of compute, is
                const float* xp = x +    // consumed at stage(it+1) pre-barrier
                    (bT + ktn*64 + 16*gw + ln15)*32 + quad*8;
                pX0 = ((const float4_a*)xp)[0];
                pX1 = ((const float4_a*)xp)[1];
                const float* tp = x + (bT + ktn*64 + kgT*8)*32 + cT;
                #pragma unroll
                for (int j = 0; j < 8; ++j) pT[j] = tp[j*32];
            }
            if (!active) continue;
            int k0 = kt * 64;

            // ---- S^T = x_k · Y^T : 4 MFMA (K=32) ----
            floatx4 s4[4];
            #pragma unroll
            for (int t = 0; t < 4; ++t) {
                union { uint4 u; short8 s; } a;
                a.u = sStage[stB + (16*t + ln15)*4 + quad];
                floatx4 c = (floatx4){0.f,0.f,0.f,0.f};
                c = MFMA16(a.s, bq, c);
                s4[t] = c;
            }

            // ---- p = exp2(s), mask only diagonal tile, P^T -> LDS ----
            unsigned long long* sP64 = (unsigned long long*)sP;
            const int pb = wave*256 + ln15*16;
            const int xk = ln15 & 14;
            if (kt == qtP) {             // block-uniform branch
                #pragma unroll
                for (int t = 0; t < 4; ++t) {
                    int keyb = k0 + 16*t + quad*4;
                    float p[4];
                    #pragma unroll
                    for (int r = 0; r < 4; ++r) {
                        p[r] = (keyb + r <= qrow) ? __builtin_amdgcn_exp2f(s4[t][r]) : 0.f;
                        l_lane += p[r];
                    }
                    unsigned long long pk =
                        ((unsigned long long)pk_bf2(p[2], p[3]) << 32) | pk_bf2(p[0], p[1]);
                    sP64[pb + ((4*t + quad) ^ xk)] = pk;
                }
            } else {
                #pragma unroll
                for (int t = 0; t < 4; ++t) {
                    float p[4];
                    #pragma unroll
                    for (int r = 0; r < 4; ++r) {
                        p[r] = __builtin_amdgcn_exp2f(s4[t][r]);
                        l_lane += p[r];
                    }
                    unsigned long long pk =
                        ((unsigned long long)pk_bf2(p[2], p[3]) << 32) | pk_bf2(p[0], p[1]);
                    sP64[pb + ((4*t + quad) ^ xk)] = pk;
                }
            }

            // ---- Z^T += x^T · P^T : 4 MFMA ----
            int h = (ln15 >> 1) & 7;
            union { uint4 u; short8 s; } p0, p1;
            p0.u = sP[wave*128 + ln15*8 + (quad ^ h)];
            p1.u = sP[wave*128 + ln15*8 + ((quad + 4) ^ h)];
            #pragma unroll
            for (int mt = 0; mt < 2; ++mt) {
                int row = 16*mt + ln15;
                union { uint4 u; short8 s; } a0, a1;
                a0.u = sStage[stB + 256 + row*8 + (quad ^ (ln15 & 7))];
                a1.u = sStage[stB + 256 + row*8 + ((4 + quad) ^ (ln15 & 7))];
                z4[mt] = MFMA16(a0.s, p0.s, z4[mt]);
                z4[mt] = MFMA16(a1.s, p1.s, z4[mt]);
            }
        }

        // ---- merge 4 groups' (Z^T, l) additively in LDS; group 0 finishes ----
        __syncthreads();                 // compute done; staging & sP free
        int li = gw*64 + lane;
        ((float*)sP)[wave*64 + lane] = l_lane;   // raw per-lane partial
        if (group != 0) {
            float4* st = (float4*)((char*)sStage + group*16384);
            st[li*2 + 0] = make_float4(z4[0][0], z4[0][1], z4[0][2], z4[0][3]);
            st[li*2 + 1] = make_float4(z4[1][0], z4[1][1], z4[1][2], z4[1][3]);
        }
        __syncthreads();
        if (group == 0) {
            float l = l_lane + ((float*)sP)[256 + li]
                    + ((float*)sP)[512 + li] + ((float*)sP)[768 + li];
            l += __shfl_xor(l, 16);      // quads hold disjoint key subsets
            l += __shfl_xor(l, 32);
            float inv = 1.f / l;
            #pragma unroll
            for (int g = 1; g < 4; ++g) {
                float4* st = (float4*)((char*)sStage + g*16384);
                float4 a = st[li*2 + 0], bb = st[li*2 + 1];
                z4[0][0]+=a.x; z4[0][1]+=a.y; z4[0][2]+=a.z; z4[0][3]+=a.w;
                z4[1][0]+=bb.x; z4[1][1]+=bb.y; z4[1][2]+=bb.z; z4[1][3]+=bb.w;
            }
            // pack merged Z as bf16 [q][c] (rows 64 B) into group-0 staging
            unsigned short* sZb = (unsigned short*)sStage;
            #pragma unroll
            for (int mt = 0; mt < 2; ++mt)
                *(ushort4_a*)(sZb + (gw*16 + ln15)*32 + 16*mt + quad*4) = pack4(z4[mt]);
            union { uint4 u; short8 s; } zb;   // same-wave readback (lgkmcnt)
            zb.u = sStage[(gw*16 + ln15)*4 + quad];
            // O^T = Wv^T · Z^T : 4 MFMA (K=32); col=q=ln15, row=d=16t+quad*4+r
            #pragma unroll
            for (int t = 0; t < 4; ++t) {
                floatx4 o = (floatx4){0.f,0.f,0.f,0.f};
                o = MFMA16(wv_f[t], zb.s, o);
                *(float4_a*)(out + (bT + q0 + gw*16 + ln15)*Dd + 16*t + quad*4)
                    = make_float4(o[0]*inv, o[1]*inv, o[2]*inv, o[3]*inv);
            }
        }
        __syncthreads();                 // merge/output done before next phase
    }
}

// ---------------------------------------------------------------------------
extern "C" void kernel_launch(void* const* d_in, const int* in_sizes, int n_in,
                              void* d_out, int out_size, void* d_ws, size_t ws_size,
                              hipStream_t stream)
{
    const float* x  = (const float*)d_in[0];
    const float* Wk = (const float*)d_in[1];   // setup_inputs order: x, Wk, Wq, Wv
    const float* Wq = (const float*)d_in[2];
    const float* Wv = (const float*)d_in[3];
    float* out = (float*)d_out;

    // 256 blocks (one per CU), 1024 threads, 96 KB LDS, uniform 17 iterations
    attn_kernel<<<Bc * 32, 1024, 0, stream>>>(x, Wk, Wq, Wv, out);
}

// Round 11
// 90.278 us; speedup vs baseline: 1.2046x; 1.1779x over previous
//
#include <hip/hip_runtime.h>
#include <hip/hip_bf16.h>

// B=8, T=4096, C=32, D=64. Causal, no 1/sqrt(D) scaling.
constexpr int Bc = 8;
constexpr int Tt = 4096;
constexpr int Dd = 64;

typedef __attribute__((ext_vector_type(8))) short short8;   // 8 bf16 = 4 VGPRs
typedef __attribute__((ext_vector_type(4))) float floatx4;  // MFMA C/D frag
typedef uint4   __attribute__((may_alias)) uint4_a;
typedef short8  __attribute__((may_alias)) short8_a;
typedef ushort4 __attribute__((may_alias)) ushort4_a;
typedef float4  __attribute__((may_alias)) float4_a;

#define MFMA16(A, B, C) __builtin_amdgcn_mfma_f32_16x16x32_bf16(A, B, C, 0, 0, 0)
constexpr float LOG2E = 1.4426950408889634f;

// ---- fast fp32 -> bf16: round-half-up (u + 0x8000), pack 2 via v_perm ----
__device__ __forceinline__ unsigned rnd16(float x) {
    unsigned u; __builtin_memcpy(&u, &x, 4); return u + 0x8000u;
}
__device__ __forceinline__ unsigned pk_bf2(float lo, float hi) {
    return __builtin_amdgcn_perm(rnd16(hi), rnd16(lo), 0x07060302);
}
__device__ __forceinline__ ushort4 pack4(floatx4 d) {
    union { unsigned u[2]; ushort4 v; } r;
    r.u[0] = pk_bf2(d[0], d[1]);
    r.u[1] = pk_bf2(d[2], d[3]);
    return r.v;
}
__device__ __forceinline__ short8 cvt8(float4 a, float4 b) {
    union { unsigned u[4]; short8 s; } r;
    r.u[0] = pk_bf2(a.x, a.y);
    r.u[1] = pk_bf2(a.z, a.w);
    r.u[2] = pk_bf2(b.x, b.y);
    r.u[3] = pk_bf2(b.z, b.w);
    return r.s;
}

// ---------------------------------------------------------------------------
// Associativity-refactored fused attention (R9 algebra):
//   G = (log2e Wq)Wk^T [32x32] once; Y = x·G per phase (effective Q);
//   S^T = x_k·Y^T (K=32, 1 MFMA per 16-key subtile); Z^T += x^T·P^T per wave;
//   O^T = Wv^T·Z^T once per phase after the additive merge.
// R11 register/memory fixes (R9/R10 post-mortems: 31 MB spill traffic at
// VGPR_Count=64 + 8 uncoalesced global loads/thread/tile):
//   - wv_f loaded only by group 0 at merge time (16 regs out of the loop).
//   - G kept in dedicated LDS (sG); gt re-read per phase (8 regs out).
//   - x^T staging derived from the SAME coalesced 32B/thread load as x_k,
//     transposed via 8 ds_write_b16 (pT[8] scatter loads gone, 8 regs out).
// Structure: 1024 thr = 4 split-K groups x 4 waves; balanced qt-pair
// (63-pr, pr) sequentially; double-buffered staging, ONE barrier per k-iter;
// prefetch issued after the barrier; no-max exp2 softmax; LDS-only merges.
// ---------------------------------------------------------------------------
__global__ __launch_bounds__(1024, 4) void attn_kernel(
    const float* __restrict__ x,
    const float* __restrict__ Wk, const float* __restrict__ Wq,
    const float* __restrict__ Wv,
    float* __restrict__ out)
{
    __shared__ uint4 sStage[4096];  // 64 KB: group g at g*1024; buf d at +d*512:
                                    //  x_k [0..255] ([key][c], 64B rows, swz)
                                    //  x^T [256..511] ([c][key], 128B rows, swz)
    __shared__ uint4 sP[2048];      // 32 KB: wave P slots (w*128); Y/l transient
    __shared__ uint4 sG[128];       // 2 KB: G^T [c'][c] bf16, persistent

    int b  = blockIdx.x & 7;
    int pr = blockIdx.x >> 3;            // 0..31
    int tid  = threadIdx.x;
    int wave = tid >> 6, lane = tid & 63;
    int group = wave >> 2, gw = wave & 3;
    int ln15 = lane & 15, quad = lane >> 4;
    size_t bT = (size_t)b * Tt;

    // staging role: group's 256 threads cover the 64x32 slab, 8 c each
    const int tg = tid & 255;
    const int srow = tg >> 2, scg = tg & 3;
    const int skg = srow >> 3, srl = srow & 7;

    // ---- G = (log2e Wq)·Wk^T [32x32], wave 0 computes -> sG (persistent) ----
    if (wave == 0) {
        floatx4 gC[2][2];
        #pragma unroll
        for (int mt = 0; mt < 2; ++mt)
            #pragma unroll
            for (int nt = 0; nt < 2; ++nt) gC[mt][nt] = (floatx4){0.f,0.f,0.f,0.f};
        #pragma unroll
        for (int kt = 0; kt < 2; ++kt) {
            short8 aG[2], bG[2];
            #pragma unroll
            for (int mt = 0; mt < 2; ++mt) {
                const float* qp = Wq + (ln15 + 16*mt)*64 + 32*kt + quad*8;
                float4 a = ((const float4_a*)qp)[0], bb = ((const float4_a*)qp)[1];
                a.x*=LOG2E; a.y*=LOG2E; a.z*=LOG2E; a.w*=LOG2E;
                bb.x*=LOG2E; bb.y*=LOG2E; bb.z*=LOG2E; bb.w*=LOG2E;
                aG[mt] = cvt8(a, bb);
                const float* kp = Wk + (ln15 + 16*mt)*64 + 32*kt + quad*8;
                bG[mt] = cvt8(((const float4_a*)kp)[0], ((const float4_a*)kp)[1]);
            }
            #pragma unroll
            for (int mt = 0; mt < 2; ++mt)
                #pragma unroll
                for (int nt = 0; nt < 2; ++nt)
                    gC[mt][nt] = MFMA16(aG[mt], bG[nt], gC[mt][nt]);
        }
        unsigned short* sGh = (unsigned short*)sG;
        #pragma unroll
        for (int mt = 0; mt < 2; ++mt)
            #pragma unroll
            for (int nt = 0; nt < 2; ++nt)
                *(ushort4_a*)(sGh + (16*nt + ln15)*32 + 16*mt + quad*4)
                    = pack4(gC[mt][nt]);
    }
    __syncthreads();

    const int gBase = group * 1024;      // group's 16 KB region (uint4 units)
    unsigned short* sYh = (unsigned short*)sP;

    for (int phase = 0; phase < 2; ++phase) {
        const int qtP = phase ? pr : 63 - pr;
        const int q0 = qtP * 64;
        const int qrow = q0 + gw*16 + ln15;

        // ---- prologue x-slab prefetch (kt = group): coalesced 32 B/thread ----
        float4 pX0, pX1;
        if (group <= qtP) {
            const float* xp = x + (bT + group*64 + srow)*32 + scg*8;
            pX0 = ((const float4_a*)xp)[0];
            pX1 = ((const float4_a*)xp)[1];
        }

        // ---- Y = x·G regen: waves 0..7, (qsub = w&3, mt = w>>2), 1 MFMA ----
        if (wave < 8) {
            int qs = wave & 3, mt = wave >> 2;
            union { uint4 u; short8 s; } g;
            g.u = sG[(16*mt + ln15)*4 + quad];   // gt re-read (not loop-live)
            const float* xp = x + (bT + q0 + qs*16 + ln15)*32 + quad*8;
            short8 xq = cvt8(((const float4_a*)xp)[0], ((const float4_a*)xp)[1]);
            floatx4 d = (floatx4){0.f,0.f,0.f,0.f};
            d = MFMA16(g.s, xq, d);      // col=q=ln15, row=yc=16mt+quad*4+r
            *(ushort4_a*)(sYh + (qs*16 + ln15)*32 + 16*mt + quad*4) = pack4(d);
        }
        __syncthreads();
        short8 bq;   // Y B-frag: (n = q = ln15, k = yc = quad*8+j), K=32
        {
            union { uint4 u; short8 s; } t0;
            t0.u = sP[(gw*16 + ln15)*4 + quad];
            bq = t0.s;
        }

        floatx4 z4[2];    // Z^T acc: (col=q=ln15, row=c'=16mt+quad*4+r)
        z4[0] = (floatx4){0.f,0.f,0.f,0.f};
        z4[1] = (floatx4){0.f,0.f,0.f,0.f};
        float l_lane = 0.f;

        const int nIter = (qtP + 4) >> 2;

        for (int it = 0; it < nIter; ++it) {
            int kt = 4*it + group;
            bool active = (kt <= qtP);
            const int stB = gBase + (it & 1) * 512;   // double buffer
            if (active) {   // stage both layouts from the one coalesced load
                unsigned u0 = pk_bf2(pX0.x, pX0.y), u1 = pk_bf2(pX0.z, pX0.w);
                unsigned u2 = pk_bf2(pX1.x, pX1.y), u3 = pk_bf2(pX1.z, pX1.w);
                uint4 xu; xu.x = u0; xu.y = u1; xu.z = u2; xu.w = u3;
                // x_k [key][c]: granule scg at scg^(row&3)
                sStage[stB + srow*4 + (scg ^ (srow & 3))] = xu;
                // x^T [c][key]: 8 b16 scatter, granule kg at kg^(c&7), c&7=j
                unsigned short* sXh = (unsigned short*)(sStage + stB + 256);
                int cb = scg * 8;
                sXh[(cb+0)*64 + ((skg ^ 0) << 3) + srl] = (unsigned short)(u0 & 0xffff);
                sXh[(cb+1)*64 + ((skg ^ 1) << 3) + srl] = (unsigned short)(u0 >> 16);
                sXh[(cb+2)*64 + ((skg ^ 2) << 3) + srl] = (unsigned short)(u1 & 0xffff);
                sXh[(cb+3)*64 + ((skg ^ 3) << 3) + srl] = (unsigned short)(u1 >> 16);
                sXh[(cb+4)*64 + ((skg ^ 4) << 3) + srl] = (unsigned short)(u2 & 0xffff);
                sXh[(cb+5)*64 + ((skg ^ 5) << 3) + srl] = (unsigned short)(u2 >> 16);
                sXh[(cb+6)*64 + ((skg ^ 6) << 3) + srl] = (unsigned short)(u3 & 0xffff);
                sXh[(cb+7)*64 + ((skg ^ 7) << 3) + srl] = (unsigned short)(u3 >> 16);
            }
            __syncthreads();             // single barrier: stage(it) visible;
                                         // buf reused at it+2, after barrier it+1
            int ktn = kt + 4;            // prefetch AFTER barrier -> in flight
            if (ktn <= qtP) {            // across all of compute
                const float* xp = x + (bT + ktn*64 + srow)*32 + scg*8;
                pX0 = ((const float4_a*)xp)[0];
                pX1 = ((const float4_a*)xp)[1];
            }
            if (!active) continue;
            int k0 = kt * 64;

            // ---- S^T = x_k · Y^T : 4 MFMA (K=32) ----
            const int xsw = quad ^ (ln15 & 3);
            floatx4 s4[4];
            #pragma unroll
            for (int t = 0; t < 4; ++t) {
                union { uint4 u; short8 s; } a;
                a.u = sStage[stB + (16*t + ln15)*4 + xsw];
                floatx4 c = (floatx4){0.f,0.f,0.f,0.f};
                c = MFMA16(a.s, bq, c);
                s4[t] = c;
            }

            // ---- p = exp2(s), mask only diagonal tile, P^T -> LDS ----
            unsigned long long* sP64 = (unsigned long long*)sP;
            const int pb = wave*256 + ln15*16;
            const int xk = ln15 & 14;
            if (kt == qtP) {             // group-uniform branch
                #pragma unroll
                for (int t = 0; t < 4; ++t) {
                    int keyb = k0 + 16*t + quad*4;
                    float p[4];
                    #pragma unroll
                    for (int r = 0; r < 4; ++r) {
                        p[r] = (keyb + r <= qrow) ? __builtin_amdgcn_exp2f(s4[t][r]) : 0.f;
                        l_lane += p[r];
                    }
                    unsigned long long pk =
                        ((unsigned long long)pk_bf2(p[2], p[3]) << 32) | pk_bf2(p[0], p[1]);
                    sP64[pb + ((4*t + quad) ^ xk)] = pk;
                }
            } else {
                #pragma unroll
                for (int t = 0; t < 4; ++t) {
                    float p[4];
                    #pragma unroll
                    for (int r = 0; r < 4; ++r) {
                        p[r] = __builtin_amdgcn_exp2f(s4[t][r]);
                        l_lane += p[r];
                    }
                    unsigned long long pk =
                        ((unsigned long long)pk_bf2(p[2], p[3]) << 32) | pk_bf2(p[0], p[1]);
                    sP64[pb + ((4*t + quad) ^ xk)] = pk;
                }
            }

            // ---- Z^T += x^T · P^T : 4 MFMA ----
            int h = (ln15 >> 1) & 7;
            union { uint4 u; short8 s; } p0, p1;
            p0.u = sP[wave*128 + ln15*8 + (quad ^ h)];
            p1.u = sP[wave*128 + ln15*8 + ((quad + 4) ^ h)];
            const int h7 = ln15 & 7;
            #pragma unroll
            for (int mt = 0; mt < 2; ++mt) {
                int row = 16*mt + ln15;
                union { uint4 u; short8 s; } a0, a1;
                a0.u = sStage[stB + 256 + row*8 + (quad ^ h7)];
                a1.u = sStage[stB + 256 + row*8 + ((quad + 4) ^ h7)];
                z4[mt] = MFMA16(a0.s, p0.s, z4[mt]);
                z4[mt] = MFMA16(a1.s, p1.s, z4[mt]);
            }
        }

        // ---- merge 4 groups' (Z^T, l) additively in LDS; group 0 finishes ----
        __syncthreads();                 // compute done; staging & sP free
        int li = gw*64 + lane;
        ((float*)sP)[wave*64 + lane] = l_lane;
        if (group != 0) {
            float4* st = (float4*)(sStage + group*1024);
            st[li*2 + 0] = make_float4(z4[0][0], z4[0][1], z4[0][2], z4[0][3]);
            st[li*2 + 1] = make_float4(z4[1][0], z4[1][1], z4[1][2], z4[1][3]);
        }
        __syncthreads();
        if (group == 0) {
            // Wv^T A-frags loaded HERE (L2-hot), not loop-live
            short8 wv_f[4];
            #pragma unroll
            for (int t = 0; t < 4; ++t) {
                int col = 16*t + ln15;
                union { unsigned u[4]; short8 s; } rv;
                #pragma unroll
                for (int jj = 0; jj < 4; ++jj) {
                    const float* v0 = Wv + (quad*8 + 2*jj) * 64 + col;
                    rv.u[jj] = pk_bf2(v0[0], v0[64]);
                }
                wv_f[t] = rv.s;
            }
            float l = l_lane + ((float*)sP)[256 + li]
                    + ((float*)sP)[512 + li] + ((float*)sP)[768 + li];
            l += __shfl_xor(l, 16);      // quads hold disjoint key subsets
            l += __shfl_xor(l, 32);
            float inv = 1.f / l;
            #pragma unroll
            for (int g = 1; g < 4; ++g) {
                float4* st = (float4*)(sStage + g*1024);
                float4 a = st[li*2 + 0], bb = st[li*2 + 1];
                z4[0][0]+=a.x; z4[0][1]+=a.y; z4[0][2]+=a.z; z4[0][3]+=a.w;
                z4[1][0]+=bb.x; z4[1][1]+=bb.y; z4[1][2]+=bb.z; z4[1][3]+=bb.w;
            }
            // pack merged Z as bf16 [q][c] into group-0 staging; same-wave readback
            unsigned short* sZb = (unsigned short*)sStage;
            #pragma unroll
            for (int mt = 0; mt < 2; ++mt)
                *(ushort4_a*)(sZb + (gw*16 + ln15)*32 + 16*mt + quad*4) = pack4(z4[mt]);
            union { uint4 u; short8 s; } zb;
            zb.u = sStage[(gw*16 + ln15)*4 + quad];
            // O^T = Wv^T · Z^T : 4 MFMA (K=32); col=q=ln15, row=d=16t+quad*4+r
            #pragma unroll
            for (int t = 0; t < 4; ++t) {
                floatx4 o = (floatx4){0.f,0.f,0.f,0.f};
                o = MFMA16(wv_f[t], zb.s, o);
                *(float4_a*)(out + (bT + q0 + gw*16 + ln15)*Dd + 16*t + quad*4)
                    = make_float4(o[0]*inv, o[1]*inv, o[2]*inv, o[3]*inv);
            }
        }
        __syncthreads();                 // merge/output done before next phase
    }
}

// ---------------------------------------------------------------------------
extern "C" void kernel_launch(void* const* d_in, const int* in_sizes, int n_in,
                              void* d_out, int out_size, void* d_ws, size_t ws_size,
                              hipStream_t stream)
{
    const float* x  = (const float*)d_in[0];
    const float* Wk = (const float*)d_in[1];   // setup_inputs order: x, Wk, Wq, Wv
    const float* Wq = (const float*)d_in[2];
    const float* Wv = (const float*)d_in[3];
    float* out = (float*)d_out;

    // 256 blocks (one per CU), 1024 threads, 98 KB LDS, uniform 17 iterations
    attn_kernel<<<Bc * 32, 1024, 0, stream>>>(x, Wk, Wq, Wv, out);
}

// Round 13
// 86.940 us; speedup vs baseline: 1.2509x; 1.0384x over previous
//
#include <hip/hip_runtime.h>
#include <hip/hip_bf16.h>

// B=8, T=4096, C=32, D=64. Causal, no 1/sqrt(D) scaling.
constexpr int Bc = 8;
constexpr int Tt = 4096;
constexpr int Dd = 64;

typedef __attribute__((ext_vector_type(8))) short short8;   // 8 bf16 = 4 VGPRs
typedef __attribute__((ext_vector_type(4))) float floatx4;  // MFMA C/D frag
typedef __attribute__((ext_vector_type(4))) __fp16 half4;   // 4 f16 = 2 VGPRs
typedef __attribute__((ext_vector_type(2))) __fp16 half2v;
typedef uint4   __attribute__((may_alias)) uint4_a;
typedef short8  __attribute__((may_alias)) short8_a;
typedef ushort4 __attribute__((may_alias)) ushort4_a;
typedef float4  __attribute__((may_alias)) float4_a;
typedef half4   __attribute__((may_alias)) half4_a;

#define MFMA16(A, B, C)  __builtin_amdgcn_mfma_f32_16x16x32_bf16(A, B, C, 0, 0, 0)
#define MFMAH16(A, B, C) __builtin_amdgcn_mfma_f32_16x16x16f16(A, B, C, 0, 0, 0)
constexpr float LOG2E = 1.4426950408889634f;

// ---- fast fp32 -> bf16: round-half-up (u + 0x8000), pack 2 via v_perm ----
__device__ __forceinline__ unsigned rnd16(float x) {
    unsigned u; __builtin_memcpy(&u, &x, 4); return u + 0x8000u;
}
__device__ __forceinline__ unsigned pk_bf2(float lo, float hi) {
    return __builtin_amdgcn_perm(rnd16(hi), rnd16(lo), 0x07060302);
}
__device__ __forceinline__ ushort4 pack4(floatx4 d) {
    union { unsigned u[2]; ushort4 v; } r;
    r.u[0] = pk_bf2(d[0], d[1]);
    r.u[1] = pk_bf2(d[2], d[3]);
    return r.v;
}
__device__ __forceinline__ short8 cvt8(float4 a, float4 b) {
    union { unsigned u[4]; short8 s; } r;
    r.u[0] = pk_bf2(a.x, a.y);
    r.u[1] = pk_bf2(a.z, a.w);
    r.u[2] = pk_bf2(b.x, b.y);
    r.u[3] = pk_bf2(b.z, b.w);
    return r.s;
}

// ---------------------------------------------------------------------------
// Associativity-refactored fused attention (R9 algebra):
//   G = (log2e Wq)Wk^T [32x32] once; Y = x·G per phase (effective Q);
//   S^T = x_k·Y^T (K=32 bf16); Z^T += x^T·P^T per wave; O^T = Wv^T·Z^T per
//   phase after the additive merge.
// R12/R13: NO P LDS round-trip. For v_mfma_f32_16x16x16_f16 the B-operand
// layout (n=lane&15, k=quad*4+j) IS the C/D layout (col=lane&15, row=quad*4+r)
// of the S^T subtiles -> masked/exp'd P feeds PV directly from registers:
//   Z^T[mt] += mfma_16x16x16_f16(x^T_frag, p_frag)  (8 small MFMA, same FLOPs)
// x^T staged as f16, [c][key] rows with 8B-granule XOR swizzle (g ^ (c&15)) ->
// conflict-free half4 A-frag reads. P conversion via cvt_pkrtz (1 op/2 vals).
// Structure (R10/R11): 1024 thr = 4 split-K groups x 4 waves; balanced qt-pair
// (63-pr, pr); double-buffered staging, ONE barrier per k-iter; prefetch after
// the barrier; no-max exp2 softmax; LDS-only merges (R7 lesson).
// ---------------------------------------------------------------------------
__global__ __launch_bounds__(1024, 4) void attn_kernel(
    const float* __restrict__ x,
    const float* __restrict__ Wk, const float* __restrict__ Wq,
    const float* __restrict__ Wv,
    float* __restrict__ out)
{
    __shared__ uint4 sStage[4096];  // 64 KB: group g at g*1024; buf d at +d*512:
                                    //  x_k bf16 [0..255] ([key][c], swz 16B)
                                    //  x^T f16 [256..511] ([c][key], swz 8B)
    __shared__ uint4 sP[256];       // 4 KB: Y transient / l-merge
    __shared__ uint4 sG[128];       // 2 KB: G^T [c'][c] bf16, persistent

    int b  = blockIdx.x & 7;
    int pr = blockIdx.x >> 3;            // 0..31
    int tid  = threadIdx.x;
    int wave = tid >> 6, lane = tid & 63;
    int group = wave >> 2, gw = wave & 3;
    int ln15 = lane & 15, quad = lane >> 4;
    size_t bT = (size_t)b * Tt;

    // staging role: group's 256 threads cover the 64x32 slab, 8 c each
    const int tg = tid & 255;
    const int srow = tg >> 2, scg = tg & 3;

    // ---- G = (log2e Wq)·Wk^T [32x32], wave 0 computes -> sG (persistent) ----
    if (wave == 0) {
        floatx4 gC[2][2];
        #pragma unroll
        for (int mt = 0; mt < 2; ++mt)
            #pragma unroll
            for (int nt = 0; nt < 2; ++nt) gC[mt][nt] = (floatx4){0.f,0.f,0.f,0.f};
        #pragma unroll
        for (int kt = 0; kt < 2; ++kt) {
            short8 aG[2], bG[2];
            #pragma unroll
            for (int mt = 0; mt < 2; ++mt) {
                const float* qp = Wq + (ln15 + 16*mt)*64 + 32*kt + quad*8;
                float4 a = ((const float4_a*)qp)[0], bb = ((const float4_a*)qp)[1];
                a.x*=LOG2E; a.y*=LOG2E; a.z*=LOG2E; a.w*=LOG2E;
                bb.x*=LOG2E; bb.y*=LOG2E; bb.z*=LOG2E; bb.w*=LOG2E;
                aG[mt] = cvt8(a, bb);
                const float* kp = Wk + (ln15 + 16*mt)*64 + 32*kt + quad*8;
                bG[mt] = cvt8(((const float4_a*)kp)[0], ((const float4_a*)kp)[1]);
            }
            #pragma unroll
            for (int mt = 0; mt < 2; ++mt)
                #pragma unroll
                for (int nt = 0; nt < 2; ++nt)
                    gC[mt][nt] = MFMA16(aG[mt], bG[nt], gC[mt][nt]);
        }
        unsigned short* sGh = (unsigned short*)sG;
        #pragma unroll
        for (int mt = 0; mt < 2; ++mt)
            #pragma unroll
            for (int nt = 0; nt < 2; ++nt)
                *(ushort4_a*)(sGh + (16*nt + ln15)*32 + 16*mt + quad*4)
                    = pack4(gC[mt][nt]);
    }
    __syncthreads();

    const int gBase = group * 1024;      // group's 16 KB region (uint4 units)
    unsigned short* sYh = (unsigned short*)sP;

    for (int phase = 0; phase < 2; ++phase) {
        const int qtP = phase ? pr : 63 - pr;
        const int q0 = qtP * 64;
        const int qrow = q0 + gw*16 + ln15;

        // ---- prologue x-slab prefetch (kt = group): coalesced 32 B/thread ----
        float4 pX0, pX1;
        if (group <= qtP) {
            const float* xp = x + (bT + group*64 + srow)*32 + scg*8;
            pX0 = ((const float4_a*)xp)[0];
            pX1 = ((const float4_a*)xp)[1];
        }

        // ---- Y = x·G regen: waves 0..7, (qsub = w&3, mt = w>>2), 1 MFMA ----
        if (wave < 8) {
            int qs = wave & 3, mt = wave >> 2;
            union { uint4 u; short8 s; } g;
            g.u = sG[(16*mt + ln15)*4 + quad];
            const float* xp = x + (bT + q0 + qs*16 + ln15)*32 + quad*8;
            short8 xq = cvt8(((const float4_a*)xp)[0], ((const float4_a*)xp)[1]);
            floatx4 d = (floatx4){0.f,0.f,0.f,0.f};
            d = MFMA16(g.s, xq, d);      // col=q=ln15, row=yc=16mt+quad*4+r
            *(ushort4_a*)(sYh + (qs*16 + ln15)*32 + 16*mt + quad*4) = pack4(d);
        }
        __syncthreads();
        short8 bq;   // Y B-frag: (n = q = ln15, k = yc = quad*8+j), K=32
        {
            union { uint4 u; short8 s; } t0;
            t0.u = sP[(gw*16 + ln15)*4 + quad];
            bq = t0.s;
        }

        floatx4 z4[2];    // Z^T acc: (col=q=ln15, row=c'=16mt+quad*4+r)
        z4[0] = (floatx4){0.f,0.f,0.f,0.f};
        z4[1] = (floatx4){0.f,0.f,0.f,0.f};
        float l_lane = 0.f;

        const int nIter = (qtP + 4) >> 2;

        for (int it = 0; it < nIter; ++it) {
            int kt = 4*it + group;
            bool active = (kt <= qtP);
            const int stB = gBase + (it & 1) * 512;   // double buffer
            if (active) {   // stage both layouts from the one coalesced load
                // x_k bf16 [key][c]: granule scg at scg^(srow&3)
                unsigned u0 = pk_bf2(pX0.x, pX0.y), u1 = pk_bf2(pX0.z, pX0.w);
                unsigned u2 = pk_bf2(pX1.x, pX1.y), u3 = pk_bf2(pX1.z, pX1.w);
                uint4 xu; xu.x = u0; xu.y = u1; xu.z = u2; xu.w = u3;
                sStage[stB + srow*4 + (scg ^ (srow & 3))] = xu;
                // x^T f16 [c][key]: rows 128 B, 8B-granule swizzle g^(c&15)
                union { half2v h; unsigned short us[2]; } w01, w23, w45, w67;
                w01.h = __builtin_amdgcn_cvt_pkrtz(pX0.x, pX0.y);
                w23.h = __builtin_amdgcn_cvt_pkrtz(pX0.z, pX0.w);
                w45.h = __builtin_amdgcn_cvt_pkrtz(pX1.x, pX1.y);
                w67.h = __builtin_amdgcn_cvt_pkrtz(pX1.z, pX1.w);
                unsigned short hv[8] = { w01.us[0], w01.us[1], w23.us[0], w23.us[1],
                                         w45.us[0], w45.us[1], w67.us[0], w67.us[1] };
                unsigned short* sXh = (unsigned short*)(sStage + stB + 256);
                const int cb = scg * 8, gx = srow >> 2, ko = srow & 3;
                #pragma unroll
                for (int jj = 0; jj < 8; ++jj) {
                    int c = cb + jj;
                    sXh[c*64 + ((gx ^ (c & 15)) << 2) + ko] = hv[jj];
                }
            }
            __syncthreads();             // single barrier: stage(it) visible;
                                         // buf reused at it+2, after barrier it+1
            int ktn = kt + 4;            // prefetch AFTER barrier -> in flight
            if (ktn <= qtP) {            // across all of compute
                const float* xp = x + (bT + ktn*64 + srow)*32 + scg*8;
                pX0 = ((const float4_a*)xp)[0];
                pX1 = ((const float4_a*)xp)[1];
            }
            if (!active) continue;
            int k0 = kt * 64;

            // ---- S^T = x_k · Y^T : 4 MFMA (K=32) ----
            const int xsw = quad ^ (ln15 & 3);
            floatx4 s4[4];
            #pragma unroll
            for (int t = 0; t < 4; ++t) {
                union { uint4 u; short8 s; } a;
                a.u = sStage[stB + (16*t + ln15)*4 + xsw];
                floatx4 c = (floatx4){0.f,0.f,0.f,0.f};
                c = MFMA16(a.s, bq, c);
                s4[t] = c;
            }

            // ---- p = exp2(s) in-register (mask only diagonal tile) ----
            if (kt == qtP) {             // group-uniform branch
                #pragma unroll
                for (int t = 0; t < 4; ++t) {
                    int keyb = k0 + 16*t + quad*4;
                    #pragma unroll
                    for (int r = 0; r < 4; ++r) {
                        float p = (keyb + r <= qrow) ? __builtin_amdgcn_exp2f(s4[t][r]) : 0.f;
                        s4[t][r] = p;
                        l_lane += p;
                    }
                }
            } else {
                #pragma unroll
                for (int t = 0; t < 4; ++t)
                    #pragma unroll
                    for (int r = 0; r < 4; ++r) {
                        float p = __builtin_amdgcn_exp2f(s4[t][r]);
                        s4[t][r] = p;
                        l_lane += p;
                    }
            }

            // ---- Z^T += x^T · P^T : 8 mfma_16x16x16_f16, P straight from
            //      registers (C-layout == B-frag layout at K=16) ----
            const unsigned short* sXh = (const unsigned short*)(sStage + stB + 256);
            #pragma unroll
            for (int t = 0; t < 4; ++t) {
                union { half2v h2[2]; half4 h4; } pb;
                pb.h2[0] = __builtin_amdgcn_cvt_pkrtz(s4[t][0], s4[t][1]);
                pb.h2[1] = __builtin_amdgcn_cvt_pkrtz(s4[t][2], s4[t][3]);
                const int gph = ((4*t + quad) ^ ln15) << 2;
                #pragma unroll
                for (int mt = 0; mt < 2; ++mt) {
                    half4 xa = *(const half4_a*)(sXh + (16*mt + ln15)*64 + gph);
                    z4[mt] = MFMAH16(xa, pb.h4, z4[mt]);
                }
            }
        }

        // ---- merge 4 groups' (Z^T, l) additively in LDS; group 0 finishes ----
        __syncthreads();                 // compute done; staging & sP free
        int li = gw*64 + lane;
        ((float*)sP)[wave*64 + lane] = l_lane;
        if (group != 0) {
            float4* st = (float4*)(sStage + group*1024);
            st[li*2 + 0] = make_float4(z4[0][0], z4[0][1], z4[0][2], z4[0][3]);
            st[li*2 + 1] = make_float4(z4[1][0], z4[1][1], z4[1][2], z4[1][3]);
        }
        __syncthreads();
        if (group == 0) {
            // Wv^T A-frags loaded HERE (L2-hot), not loop-live
            short8 wv_f[4];
            #pragma unroll
            for (int t = 0; t < 4; ++t) {
                int col = 16*t + ln15;
                union { unsigned u[4]; short8 s; } rv;
                #pragma unroll
                for (int jj = 0; jj < 4; ++jj) {
                    const float* v0 = Wv + (quad*8 + 2*jj) * 64 + col;
                    rv.u[jj] = pk_bf2(v0[0], v0[64]);
                }
                wv_f[t] = rv.s;
            }
            float l = l_lane + ((float*)sP)[256 + li]
                    + ((float*)sP)[512 + li] + ((float*)sP)[768 + li];
            l += __shfl_xor(l, 16);      // quads hold disjoint key subsets
            l += __shfl_xor(l, 32);
            float inv = 1.f / l;
            #pragma unroll
            for (int g = 1; g < 4; ++g) {
                float4* st = (float4*)(sStage + g*1024);
                float4 a = st[li*2 + 0], bb = st[li*2 + 1];
                z4[0][0]+=a.x; z4[0][1]+=a.y; z4[0][2]+=a.z; z4[0][3]+=a.w;
                z4[1][0]+=bb.x; z4[1][1]+=bb.y; z4[1][2]+=bb.z; z4[1][3]+=bb.w;
            }
            // pack merged Z as bf16 [q][c] into group-0 staging; same-wave readback
            unsigned short* sZb = (unsigned short*)sStage;
            #pragma unroll
            for (int mt = 0; mt < 2; ++mt)
                *(ushort4_a*)(sZb + (gw*16 + ln15)*32 + 16*mt + quad*4) = pack4(z4[mt]);
            union { uint4 u; short8 s; } zb;
            zb.u = sStage[(gw*16 + ln15)*4 + quad];
            // O^T = Wv^T · Z^T : 4 MFMA (K=32); col=q=ln15, row=d=16t+quad*4+r
            #pragma unroll
            for (int t = 0; t < 4; ++t) {
                floatx4 o = (floatx4){0.f,0.f,0.f,0.f};
                o = MFMA16(wv_f[t], zb.s, o);
                *(float4_a*)(out + (bT + q0 + gw*16 + ln15)*Dd + 16*t + quad*4)
                    = make_float4(o[0]*inv, o[1]*inv, o[2]*inv, o[3]*inv);
            }
        }
        __syncthreads();                 // merge/output done before next phase
    }
}

// ---------------------------------------------------------------------------
extern "C" void kernel_launch(void* const* d_in, const int* in_sizes, int n_in,
                              void* d_out, int out_size, void* d_ws, size_t ws_size,
                              hipStream_t stream)
{
    const float* x  = (const float*)d_in[0];
    const float* Wk = (const float*)d_in[1];   // setup_inputs order: x, Wk, Wq, Wv
    const float* Wq = (const float*)d_in[2];
    const float* Wv = (const float*)d_in[3];
    float* out = (float*)d_out;

    // 256 blocks (one per CU), 1024 threads, 70 KB LDS, uniform 17 iterations
    attn_kernel<<<Bc * 32, 1024, 0, stream>>>(x, Wk, Wq, Wv, out);
}